// Round 4
// baseline (217.303 us; speedup 1.0000x reference)
//
#include <hip/hip_runtime.h>
#include <hip/hip_fp16.h>

// Problem constants
#define OOv   200
#define KKv   1600
#define OPAD  208             // 13 col-tiles of 16
#define NCHUNK 50             // K=32 chunks
#define CHUNK_BYTES 13312     // one K=32 chunk of W-fp16 (208*4 slots * 16B)
#define XSTR 40               // halfs per x row (80 B, mult of 16)
#define YSTR 56               // halfs per y row (112 B; 28-dw stride = 2-way banks, free)

typedef _Float16 half8  __attribute__((ext_vector_type(8)));
typedef _Float16 half2v __attribute__((ext_vector_type(2)));
typedef __attribute__((ext_vector_type(4))) float floatx4;

// ---------------------------------------------------------------------------
// Pre-kernel: W [200][1600] fp32 -> Wh fp16, K-chunk-major, 16B-slot swizzled.
// idx = c*6656 + slot*8 + j ; slot = o*4 + (kg ^ ((o>>1)&3)) ; k = c*32+kg*8+j
// ---------------------------------------------------------------------------
__global__ void wb_convert_kernel(const float* __restrict__ W,
                                  unsigned short* __restrict__ Wh) {
    int idx = blockIdx.x * 256 + threadIdx.x;
    if (idx >= NCHUNK * OPAD * 32) return;     // 332800
    int j    = idx & 7;
    int slot = (idx >> 3) % (OPAD * 4);
    int c    = (idx >> 3) / (OPAD * 4);
    int o    = slot >> 2;
    int kgs  = slot & 3;
    int kg   = kgs ^ ((o >> 1) & 3);
    int k    = c * 32 + kg * 8 + j;
    float v  = (o < OOv) ? W[o * KKv + k] : 0.0f;
    union { _Float16 h; unsigned short u; } cv; cv.h = (_Float16)v;
    Wh[idx] = cv.u;
}

// ---------------------------------------------------------------------------
// One K=32 step, barrier-free. W fragments live in registers, double-buffered:
//  (a) issue 7 global_load_dwordx4 for chunk c+1 into nxt (L1/L2-resident Wh;
//      register destinations -> compiler emits exactly-counted vmcnt, no
//      LDS-DMA alias conservatism)
//  (b) yv ds_read + af build (x*y elementwise) -- ylds/xq immutable
//  (c) MFMA cluster on cur (chunk c's registers, loaded last step) under
//      setprio(1); waves free-run so the SIMD overlaps one wave's (a) with
//      the other wave's (c).
// ---------------------------------------------------------------------------
template<int P, bool PREF>
__device__ __forceinline__ void gstep(
        const char* wnext,                 // Wh + (c+1)*CHUNK_BYTES
        half8 (&cur)[7], half8 (&nxt)[7],
        const char* (&ybase)[4], half8 (&xq)[4],
        int bfoff, int ntiles, bool w1, bool w2, bool w3,
        floatx4 (&acc)[4][7])
{
    constexpr int R32a[5] = {0, 64, 48, 32, 16};  // (32p mod 40) in bytes
    constexpr int B5a[5]  = {0, 0, 1, 2, 3};
    constexpr int WKa[5]  = {0, 1, 2, 3, 0};
    constexpr int pm = P % 5, pd = P / 5;
    constexpr int yimm  = R32a[pm];
    constexpr int dbase = B5a[pm] + 4 * pd;
    constexpr int wk    = WKa[pm];
    const bool use = (wk == 1) ? w1 : (wk == 2) ? w2 : (wk == 3) ? w3 : false;

    // (a) prefetch next chunk's B-fragments straight from global (L2-hot)
    if constexpr (PREF) {
#pragma unroll
        for (int ct = 0; ct < 7; ++ct)
            if (ct < ntiles)
                nxt[ct] = *(const half8*)(wnext + bfoff + ct * 1024);
    }

    // (b) A-fragments: af[rt] = broadcast(x elem) * y window
    half8 af[4];
#pragma unroll
    for (int rt = 0; rt < 4; ++rt) {
        half8 yv = *(const half8*)(ybase[rt] + (yimm - (use ? 80 : 0)));
        _Float16 e;
        if constexpr (wk == 0) {
            e = xq[rt][dbase];             // use==false at compile time
        } else {
            e = use ? xq[rt][dbase + 1] : xq[rt][dbase];
        }
        half8 xsp = {e, e, e, e, e, e, e, e};
        af[rt] = xsp * yv;
    }

    // (c) MFMA cluster on current chunk's registers
    __builtin_amdgcn_s_setprio(1);
#pragma unroll
    for (int ct = 0; ct < 7; ++ct)
        if (ct < ntiles)
#pragma unroll
            for (int rt = 0; rt < 4; ++rt)
                acc[rt][ct] = __builtin_amdgcn_mfma_f32_16x16x32_f16(
                    af[rt], cur[ct], acc[rt][ct], 0, 0, 0);
    __builtin_amdgcn_s_setprio(0);
}

// ---------------------------------------------------------------------------
// Main kernel: 512 blocks x 256 thr, 128 rows x 208 cols per block.
// W is NOT staged in LDS: each wave streams its 7 KB/step of W-fragments
// from L2 (Wh = 0.67 MB, resident in every XCD L2; both co-resident blocks
// read the same chunk -> L1 reuse). K-loop has ZERO barriers -- only the
// x/y-publish barrier after the prologue. LDS = x/y only (24.6 KB).
// ---------------------------------------------------------------------------
__global__ __launch_bounds__(256, 2) void cin_mfma_kernel(
        const float* __restrict__ X, const float* __restrict__ Y,
        const unsigned short* __restrict__ Wh, float* __restrict__ Out) {
    __shared__ __align__(16) _Float16 xlds[128 * XSTR];            // 10240
    __shared__ __align__(16) _Float16 ylds[128 * YSTR];            // 14336

    const int tid     = threadIdx.x;
    const int wave    = tid >> 6;
    const int lane    = tid & 63;
    const int li      = lane & 15;
    const int kg      = lane >> 4;
    const int rowhalf = wave & 1;
    const int colgrp  = wave >> 1;
    const int ntiles  = colgrp ? 6 : 7;
    const int obase   = colgrp * 112;
    const long blockbase = (long)blockIdx.x * 128;

    // ---- prologue: stage x,y (128 rows x 40) as fp16
    const float* xg = X + blockbase * 40;
    const float* yg = Y + blockbase * 40;
    for (int i = tid; i < 1280; i += 256) {
        int r  = i / 10;
        int c4 = (i % 10) * 4;                 // 40 % 4 == 0: row-aligned
        floatx4 vx = *(const floatx4*)(xg + i * 4);
        floatx4 vy = *(const floatx4*)(yg + i * 4);
        union { half2v h[2]; unsigned long long u; } px, py;
        px.h[0] = (half2v){(_Float16)vx.x, (_Float16)vx.y};
        px.h[1] = (half2v){(_Float16)vx.z, (_Float16)vx.w};
        py.h[0] = (half2v){(_Float16)vy.x, (_Float16)vy.y};
        py.h[1] = (half2v){(_Float16)vy.z, (_Float16)vy.w};
        *(unsigned long long*)(xlds + r * XSTR + c4) = px.u;
        *(unsigned long long*)(ylds + r * YSTR + c4) = py.u;
    }
    __syncthreads();    // the ONLY barrier

    floatx4 acc[4][7];
#pragma unroll
    for (int rt = 0; rt < 4; ++rt)
#pragma unroll
        for (int ct = 0; ct < 7; ++ct)
            acc[rt][ct] = (floatx4){0.f, 0.f, 0.f, 0.f};

    const int rowb = rowhalf * 64 + li;
    const char* ybase[4];
    const char* xbase[4];
#pragma unroll
    for (int rt = 0; rt < 4; ++rt) {
        int row = rowb + rt * 16;
        ybase[rt] = (const char*)ylds + row * (YSTR * 2) + kg * 16;
        xbase[rt] = (const char*)xlds + row * (XSTR * 2);
    }
    const bool w1 = kg >= 1, w2 = kg >= 2, w3 = kg >= 3;

    // per-lane B-frag offset inside a chunk (swizzled slots, bank-uniform in
    // the old LDS layout; now simply the byte offset within the global chunk)
    const int bfoff = (obase + li) * 64 + ((kg ^ ((li >> 1) & 3)) * 16);

    const char* wb = (const char*)Wh;

    // preload chunk 0 into bfA
    half8 bfA[7], bfB[7];
#pragma unroll
    for (int ct = 0; ct < 7; ++ct)
        if (ct < ntiles)
            bfA[ct] = *(const half8*)(wb + bfoff + ct * 1024);

#define GSTEP(PP, PR, CUR, NXT) \
    gstep<PP, PR>(wg + (PP + 1) * CHUNK_BYTES, CUR, NXT, ybase, xq, \
                  bfoff, ntiles, w1, w2, w3, acc)

#pragma unroll 1
    for (int g = 0; g < 4; ++g) {
        // x window for this group: elements 8g..8g+7 per row
        half8 xq[4];
#pragma unroll
        for (int rt = 0; rt < 4; ++rt)
            xq[rt] = *(const half8*)(xbase[rt] + g * 16);
        const char* wg = wb + (size_t)g * 10 * CHUNK_BYTES;
        GSTEP(0, true, bfA, bfB);
        GSTEP(1, true, bfB, bfA);
        GSTEP(2, true, bfA, bfB);
        GSTEP(3, true, bfB, bfA);
        GSTEP(4, true, bfA, bfB);
        GSTEP(5, true, bfB, bfA);
        GSTEP(6, true, bfA, bfB);
        GSTEP(7, true, bfB, bfA);
        GSTEP(8, true, bfA, bfB);
        GSTEP(9, true, bfB, bfA);   // prefetches chunk 10(g+1) into bfA
    }
    // ---- peeled group g=4 (chunks 40..49): last step has nothing to prefetch
    {
        half8 xq[4];
#pragma unroll
        for (int rt = 0; rt < 4; ++rt)
            xq[rt] = *(const half8*)(xbase[rt] + 4 * 16);
        const char* wg = wb + (size_t)4 * 10 * CHUNK_BYTES;
        GSTEP(0, true, bfA, bfB);
        GSTEP(1, true, bfB, bfA);
        GSTEP(2, true, bfA, bfB);
        GSTEP(3, true, bfB, bfA);
        GSTEP(4, true, bfA, bfB);
        GSTEP(5, true, bfB, bfA);
        GSTEP(6, true, bfA, bfB);
        GSTEP(7, true, bfB, bfA);
        GSTEP(8, true, bfA, bfB);
        GSTEP(9, false, bfB, bfA);  // chunk 49: compute only
    }
#undef GSTEP

    // ---- epilogue: C/D layout col = lane&15, row = (lane>>4)*4 + reg  [m89]
#pragma unroll
    for (int rt = 0; rt < 4; ++rt) {
#pragma unroll
        for (int ct = 0; ct < 7; ++ct) {
            if (ct >= ntiles) continue;
            int gcol = obase + ct * 16 + li;
            if (gcol < OOv) {
#pragma unroll
                for (int r4 = 0; r4 < 4; ++r4) {
                    long grow = blockbase + rowhalf * 64 + rt * 16 + kg * 4 + r4;
                    Out[grow * OOv + gcol] = acc[rt][ct][r4];
                }
            }
        }
    }
}

extern "C" void kernel_launch(void* const* d_in, const int* in_sizes, int n_in,
                              void* d_out, int out_size, void* d_ws, size_t ws_size,
                              hipStream_t stream) {
    (void)in_sizes; (void)n_in; (void)out_size; (void)ws_size;
    const float* X = (const float*)d_in[0];
    const float* Y = (const float*)d_in[1];
    const float* W = (const float*)d_in[2];
    float* Out = (float*)d_out;
    unsigned short* Wh = (unsigned short*)d_ws;   // 665,600 B scratch

    wb_convert_kernel<<<1300, 256, 0, stream>>>(W, Wh);
    cin_mfma_kernel<<<512, 256, 0, stream>>>(X, Y, Wh, Out);
}

// Round 5
// 132.360 us; speedup vs baseline: 1.6418x; 1.6418x over previous
//
#include <hip/hip_runtime.h>
#include <hip/hip_fp16.h>

// Problem constants
#define OOv   200
#define KKv   1600
#define OPAD  208             // 13 col-tiles of 16
#define NCHUNK 50             // K=32 chunks
#define CHUNK_BYTES 13312     // one K=32 chunk of W-fp16 (208*4 slots * 16B)
#define XSTR 40               // halfs per x row (80 B, mult of 16)
#define YSTR 56               // halfs per y row (112 B; 28-dw stride = 2-way banks, free)

typedef _Float16 half8  __attribute__((ext_vector_type(8)));
typedef _Float16 half2v __attribute__((ext_vector_type(2)));
typedef __attribute__((ext_vector_type(4))) float floatx4;

// ---------------------------------------------------------------------------
// Pre-kernel: W [200][1600] fp32 -> Wh fp16, K-chunk-major, 16B-slot swizzled.
// idx = c*6656 + slot*8 + j ; slot = o*4 + (kg ^ ((o>>1)&3)) ; k = c*32+kg*8+j
// ---------------------------------------------------------------------------
__global__ void wb_convert_kernel(const float* __restrict__ W,
                                  unsigned short* __restrict__ Wh) {
    int idx = blockIdx.x * 256 + threadIdx.x;
    if (idx >= NCHUNK * OPAD * 32) return;     // 332800
    int j    = idx & 7;
    int slot = (idx >> 3) % (OPAD * 4);
    int c    = (idx >> 3) / (OPAD * 4);
    int o    = slot >> 2;
    int kgs  = slot & 3;
    int kg   = kgs ^ ((o >> 1) & 3);
    int k    = c * 32 + kg * 8 + j;
    float v  = (o < OOv) ? W[o * KKv + k] : 0.0f;
    union { _Float16 h; unsigned short u; } cv; cv.h = (_Float16)v;
    Wh[idx] = cv.u;
}

// ---------------------------------------------------------------------------
// One K=32 step, barrier-free, single-buffered.
//  (a) load this chunk's NT B-fragments from global (Wh is L2-resident;
//      the 2 co-resident blocks read the same bytes -> L1 dedup)
//  (b) af build (y ds_read + x broadcast-mul) covers part of the load wait
//  (c) MFMA cluster under setprio(1); waves free-run, so each SIMD's other
//      wave MFMAs while this one waits on L2.
// bf is a short-lived per-step local: the register allocator recycles it
// every step, and any cross-step hoisting the scheduler does is voluntary
// and pressure-aware (round-4 lesson: forced persistent double-buffers
// spilled the 112-AGPR accumulator -> 150 MB of scratch traffic).
// ---------------------------------------------------------------------------
template<int NT, int P>
__device__ __forceinline__ void gstep(
        const char* wg,                    // Wh + g*10*CHUNK_BYTES
        int bfoff,
        const char* (&ybase)[4], half8 (&xq)[4],
        bool w1, bool w2, bool w3,
        floatx4 (&acc)[4][7])
{
    constexpr int R32a[5] = {0, 64, 48, 32, 16};  // (32p mod 40) in bytes
    constexpr int B5a[5]  = {0, 0, 1, 2, 3};
    constexpr int WKa[5]  = {0, 1, 2, 3, 0};
    constexpr int pm = P % 5, pd = P / 5;
    constexpr int yimm  = R32a[pm];
    constexpr int dbase = B5a[pm] + 4 * pd;
    constexpr int wk    = WKa[pm];
    const bool use = (wk == 1) ? w1 : (wk == 2) ? w2 : (wk == 3) ? w3 : false;

    // (a) B-fragments straight from global (L1/L2-hot)
    half8 bf[NT];
#pragma unroll
    for (int ct = 0; ct < NT; ++ct)
        bf[ct] = *(const half8*)(wg + (size_t)P * CHUNK_BYTES + bfoff + ct * 1024);

    // (b) A-fragments: af[rt] = broadcast(x elem) * y window
    half8 af[4];
#pragma unroll
    for (int rt = 0; rt < 4; ++rt) {
        half8 yv = *(const half8*)(ybase[rt] + (yimm - (use ? 80 : 0)));
        _Float16 e;
        if constexpr (wk == 0) {
            e = xq[rt][dbase];             // use==false at compile time
        } else {
            e = use ? xq[rt][dbase + 1] : xq[rt][dbase];
        }
        half8 xsp = {e, e, e, e, e, e, e, e};
        af[rt] = xsp * yv;
    }

    // (c) MFMA cluster
    __builtin_amdgcn_s_setprio(1);
#pragma unroll
    for (int ct = 0; ct < NT; ++ct)
#pragma unroll
        for (int rt = 0; rt < 4; ++rt)
            acc[rt][ct] = __builtin_amdgcn_mfma_f32_16x16x32_f16(
                af[rt], bf[ct], acc[rt][ct], 0, 0, 0);
    __builtin_amdgcn_s_setprio(0);
}

template<int NT>
__device__ __forceinline__ void kloop(
        const char* wb, int bfoff,
        const char* (&ybase)[4], const char* (&xbase)[4],
        bool w1, bool w2, bool w3,
        floatx4 (&acc)[4][7])
{
#pragma unroll 1
    for (int g = 0; g < 5; ++g) {
        // x window for this group: elements 8g..8g+7 per row
        half8 xq[4];
#pragma unroll
        for (int rt = 0; rt < 4; ++rt)
            xq[rt] = *(const half8*)(xbase[rt] + g * 16);
        const char* wg = wb + (size_t)g * 10 * CHUNK_BYTES;
        gstep<NT, 0>(wg, bfoff, ybase, xq, w1, w2, w3, acc);
        gstep<NT, 1>(wg, bfoff, ybase, xq, w1, w2, w3, acc);
        gstep<NT, 2>(wg, bfoff, ybase, xq, w1, w2, w3, acc);
        gstep<NT, 3>(wg, bfoff, ybase, xq, w1, w2, w3, acc);
        gstep<NT, 4>(wg, bfoff, ybase, xq, w1, w2, w3, acc);
        gstep<NT, 5>(wg, bfoff, ybase, xq, w1, w2, w3, acc);
        gstep<NT, 6>(wg, bfoff, ybase, xq, w1, w2, w3, acc);
        gstep<NT, 7>(wg, bfoff, ybase, xq, w1, w2, w3, acc);
        gstep<NT, 8>(wg, bfoff, ybase, xq, w1, w2, w3, acc);
        gstep<NT, 9>(wg, bfoff, ybase, xq, w1, w2, w3, acc);
    }
}

// ---------------------------------------------------------------------------
// Main kernel: 512 blocks x 256 thr, 128 rows x 208 cols per block.
// W is NOT staged in LDS: each wave streams 7 KB/step of W-fragments from
// L1/L2 (Wh = 0.67 MB, resident in every XCD L2; both co-resident blocks
// read the same chunk bytes -> L1 serves the second reader). K-loop has
// ZERO barriers -- only the x/y-publish barrier after the prologue.
// LDS = x/y only (24.6 KB). NT (7|6 col-tiles) is a template parameter so
// the hot loop has no runtime conditionals.
// ---------------------------------------------------------------------------
__global__ __launch_bounds__(256, 2) void cin_mfma_kernel(
        const float* __restrict__ X, const float* __restrict__ Y,
        const unsigned short* __restrict__ Wh, float* __restrict__ Out) {
    __shared__ __align__(16) _Float16 xlds[128 * XSTR];            // 10240
    __shared__ __align__(16) _Float16 ylds[128 * YSTR];            // 14336

    const int tid     = threadIdx.x;
    const int wave    = tid >> 6;
    const int lane    = tid & 63;
    const int li      = lane & 15;
    const int kg      = lane >> 4;
    const int rowhalf = wave & 1;
    const int colgrp  = wave >> 1;
    const int ntiles  = colgrp ? 6 : 7;
    const int obase   = colgrp * 112;
    const long blockbase = (long)blockIdx.x * 128;

    // ---- prologue: stage x,y (128 rows x 40) as fp16
    const float* xg = X + blockbase * 40;
    const float* yg = Y + blockbase * 40;
    for (int i = tid; i < 1280; i += 256) {
        int r  = i / 10;
        int c4 = (i % 10) * 4;                 // 40 % 4 == 0: row-aligned
        floatx4 vx = *(const floatx4*)(xg + i * 4);
        floatx4 vy = *(const floatx4*)(yg + i * 4);
        union { half2v h[2]; unsigned long long u; } px, py;
        px.h[0] = (half2v){(_Float16)vx.x, (_Float16)vx.y};
        px.h[1] = (half2v){(_Float16)vx.z, (_Float16)vx.w};
        py.h[0] = (half2v){(_Float16)vy.x, (_Float16)vy.y};
        py.h[1] = (half2v){(_Float16)vy.z, (_Float16)vy.w};
        *(unsigned long long*)(xlds + r * XSTR + c4) = px.u;
        *(unsigned long long*)(ylds + r * YSTR + c4) = py.u;
    }
    __syncthreads();    // the ONLY barrier

    floatx4 acc[4][7];
#pragma unroll
    for (int rt = 0; rt < 4; ++rt)
#pragma unroll
        for (int ct = 0; ct < 7; ++ct)
            acc[rt][ct] = (floatx4){0.f, 0.f, 0.f, 0.f};

    const int rowb = rowhalf * 64 + li;
    const char* ybase[4];
    const char* xbase[4];
#pragma unroll
    for (int rt = 0; rt < 4; ++rt) {
        int row = rowb + rt * 16;
        ybase[rt] = (const char*)ylds + row * (YSTR * 2) + kg * 16;
        xbase[rt] = (const char*)xlds + row * (XSTR * 2);
    }
    const bool w1 = kg >= 1, w2 = kg >= 2, w3 = kg >= 3;

    // per-lane B-frag byte offset inside a global W chunk (16B-slot swizzle)
    const int bfoff = (obase + li) * 64 + ((kg ^ ((li >> 1) & 3)) * 16);

    const char* wb = (const char*)Wh;

    if (colgrp == 0)
        kloop<7>(wb, bfoff, ybase, xbase, w1, w2, w3, acc);
    else
        kloop<6>(wb, bfoff, ybase, xbase, w1, w2, w3, acc);

    // ---- epilogue: C/D layout col = lane&15, row = (lane>>4)*4 + reg  [m89]
#pragma unroll
    for (int rt = 0; rt < 4; ++rt) {
#pragma unroll
        for (int ct = 0; ct < 7; ++ct) {
            if (ct >= ntiles) continue;
            int gcol = obase + ct * 16 + li;
            if (gcol < OOv) {
#pragma unroll
                for (int r4 = 0; r4 < 4; ++r4) {
                    long grow = blockbase + rowhalf * 64 + rt * 16 + kg * 4 + r4;
                    Out[grow * OOv + gcol] = acc[rt][ct][r4];
                }
            }
        }
    }
}

extern "C" void kernel_launch(void* const* d_in, const int* in_sizes, int n_in,
                              void* d_out, int out_size, void* d_ws, size_t ws_size,
                              hipStream_t stream) {
    (void)in_sizes; (void)n_in; (void)out_size; (void)ws_size;
    const float* X = (const float*)d_in[0];
    const float* Y = (const float*)d_in[1];
    const float* W = (const float*)d_in[2];
    float* Out = (float*)d_out;
    unsigned short* Wh = (unsigned short*)d_ws;   // 665,600 B scratch

    wb_convert_kernel<<<1300, 256, 0, stream>>>(W, Wh);
    cin_mfma_kernel<<<512, 256, 0, stream>>>(X, Y, Wh, Out);
}

// Round 6
// 131.298 us; speedup vs baseline: 1.6550x; 1.0081x over previous
//
#include <hip/hip_runtime.h>
#include <hip/hip_fp16.h>

// Problem constants
#define OOv   200
#define KKv   1600
#define OPAD  208             // 13 col-tiles of 16
#define NCHUNK 50             // K=32 chunks
#define CHUNK_BYTES 13312     // one K=32 chunk of W-fp16 (208*4 slots * 16B)
#define XSTR 40               // halfs per x row (80 B, mult of 16)
#define YSTR 56               // halfs per y row (112 B; 28-dw stride = 2-way banks, free)
#define ROWS 64               // rows per block (halved: acc 112 -> 56 AGPR)

typedef _Float16 half8  __attribute__((ext_vector_type(8)));
typedef _Float16 half2v __attribute__((ext_vector_type(2)));
typedef __attribute__((ext_vector_type(4))) float floatx4;

// ---------------------------------------------------------------------------
// Pre-kernel: W [200][1600] fp32 -> Wh fp16, K-chunk-major, 16B-slot swizzled.
// idx = c*6656 + slot*8 + j ; slot = o*4 + (kg ^ ((o>>1)&3)) ; k = c*32+kg*8+j
// ---------------------------------------------------------------------------
__global__ void wb_convert_kernel(const float* __restrict__ W,
                                  unsigned short* __restrict__ Wh) {
    int idx = blockIdx.x * 256 + threadIdx.x;
    if (idx >= NCHUNK * OPAD * 32) return;     // 332800
    int j    = idx & 7;
    int slot = (idx >> 3) % (OPAD * 4);
    int c    = (idx >> 3) / (OPAD * 4);
    int o    = slot >> 2;
    int kgs  = slot & 3;
    int kg   = kgs ^ ((o >> 1) & 3);
    int k    = c * 32 + kg * 8 + j;
    float v  = (o < OOv) ? W[o * KKv + k] : 0.0f;
    union { _Float16 h; unsigned short u; } cv; cv.h = (_Float16)v;
    Wh[idx] = cv.u;
}

// ---------------------------------------------------------------------------
// One K=32 step, barrier-free, single-buffered, rt=2.
//  (a) load this chunk's NT B-fragments from global (Wh L2-resident; the
//      3-4 co-resident blocks/CU read the same bytes -> L1/L2 reuse)
//  (b) af build (y ds_read + x broadcast-mul) covers part of the load wait
//  (c) MFMA cluster under setprio(1); 3 free-running waves/SIMD at drifting
//      phases fill each other's load-wait (the round-5 lesson: 2 waves/SIMD
//      at 240 regs cannot hide ~1800 cyc/step of latency; occupancy, not
//      schedule, was the binding constraint).
// ---------------------------------------------------------------------------
template<int NT, int P>
__device__ __forceinline__ void gstep(
        const char* wg,                    // Wh + g*10*CHUNK_BYTES
        int bfoff,
        const char* (&ybase)[2], half8 (&xq)[2],
        bool w1, bool w2, bool w3,
        floatx4 (&acc)[2][7])
{
    constexpr int R32a[5] = {0, 64, 48, 32, 16};  // (32p mod 40) in bytes
    constexpr int B5a[5]  = {0, 0, 1, 2, 3};
    constexpr int WKa[5]  = {0, 1, 2, 3, 0};
    constexpr int pm = P % 5, pd = P / 5;
    constexpr int yimm  = R32a[pm];
    constexpr int dbase = B5a[pm] + 4 * pd;
    constexpr int wk    = WKa[pm];
    const bool use = (wk == 1) ? w1 : (wk == 2) ? w2 : (wk == 3) ? w3 : false;

    // (a) B-fragments straight from global (L1/L2-hot)
    half8 bf[NT];
#pragma unroll
    for (int ct = 0; ct < NT; ++ct)
        bf[ct] = *(const half8*)(wg + (size_t)P * CHUNK_BYTES + bfoff + ct * 1024);

    // (b) A-fragments: af[rt] = broadcast(x elem) * y window
    half8 af[2];
#pragma unroll
    for (int rt = 0; rt < 2; ++rt) {
        half8 yv = *(const half8*)(ybase[rt] + (yimm - (use ? 80 : 0)));
        _Float16 e;
        if constexpr (wk == 0) {
            e = xq[rt][dbase];             // use==false at compile time
        } else {
            e = use ? xq[rt][dbase + 1] : xq[rt][dbase];
        }
        half8 xsp = {e, e, e, e, e, e, e, e};
        af[rt] = xsp * yv;
    }

    // (c) MFMA cluster
    __builtin_amdgcn_s_setprio(1);
#pragma unroll
    for (int ct = 0; ct < NT; ++ct)
#pragma unroll
        for (int rt = 0; rt < 2; ++rt)
            acc[rt][ct] = __builtin_amdgcn_mfma_f32_16x16x32_f16(
                af[rt], bf[ct], acc[rt][ct], 0, 0, 0);
    __builtin_amdgcn_s_setprio(0);
}

template<int NT>
__device__ __forceinline__ void kloop(
        const char* wb, int bfoff,
        const char* (&ybase)[2], const char* (&xbase)[2],
        bool w1, bool w2, bool w3,
        floatx4 (&acc)[2][7])
{
#pragma unroll 1
    for (int g = 0; g < 5; ++g) {
        // x window for this group: elements 8g..8g+7 per row
        half8 xq[2];
#pragma unroll
        for (int rt = 0; rt < 2; ++rt)
            xq[rt] = *(const half8*)(xbase[rt] + g * 16);
        const char* wg = wb + (size_t)g * 10 * CHUNK_BYTES;
        gstep<NT, 0>(wg, bfoff, ybase, xq, w1, w2, w3, acc);
        gstep<NT, 1>(wg, bfoff, ybase, xq, w1, w2, w3, acc);
        gstep<NT, 2>(wg, bfoff, ybase, xq, w1, w2, w3, acc);
        gstep<NT, 3>(wg, bfoff, ybase, xq, w1, w2, w3, acc);
        gstep<NT, 4>(wg, bfoff, ybase, xq, w1, w2, w3, acc);
        gstep<NT, 5>(wg, bfoff, ybase, xq, w1, w2, w3, acc);
        gstep<NT, 6>(wg, bfoff, ybase, xq, w1, w2, w3, acc);
        gstep<NT, 7>(wg, bfoff, ybase, xq, w1, w2, w3, acc);
        gstep<NT, 8>(wg, bfoff, ybase, xq, w1, w2, w3, acc);
        gstep<NT, 9>(wg, bfoff, ybase, xq, w1, w2, w3, acc);
    }
}

// ---------------------------------------------------------------------------
// Main kernel: 1024 blocks x 256 thr, 64 rows x 208 cols per block.
// acc[2][7] = 56 AGPR/wave + ~100 VGPR -> fits 3 waves/SIMD under
// __launch_bounds__(256,3); LDS 12.3 KB/block -> 3 blocks/CU resident.
// W is streamed from L1/L2 per step (Wh = 0.67 MB, L2-resident; co-resident
// blocks share chunk bytes). K-loop has ZERO barriers.
// ---------------------------------------------------------------------------
__global__ __launch_bounds__(256, 3) void cin_mfma_kernel(
        const float* __restrict__ X, const float* __restrict__ Y,
        const unsigned short* __restrict__ Wh, float* __restrict__ Out) {
    __shared__ __align__(16) _Float16 xlds[ROWS * XSTR];           // 5120
    __shared__ __align__(16) _Float16 ylds[ROWS * YSTR];           // 7168

    const int tid     = threadIdx.x;
    const int wave    = tid >> 6;
    const int lane    = tid & 63;
    const int li      = lane & 15;
    const int kg      = lane >> 4;
    const int rowhalf = wave & 1;          // 32-row half
    const int colgrp  = wave >> 1;         // 0: 7 tiles, 1: 6 tiles
    const int ntiles  = colgrp ? 6 : 7;
    const int obase   = colgrp * 112;
    const long blockbase = (long)blockIdx.x * ROWS;

    // ---- prologue: stage x,y (64 rows x 40) as fp16
    const float* xg = X + blockbase * 40;
    const float* yg = Y + blockbase * 40;
    for (int i = tid; i < ROWS * 10; i += 256) {   // 640 quads
        int r  = i / 10;
        int c4 = (i % 10) * 4;                 // 40 % 4 == 0: row-aligned
        floatx4 vx = *(const floatx4*)(xg + i * 4);
        floatx4 vy = *(const floatx4*)(yg + i * 4);
        union { half2v h[2]; unsigned long long u; } px, py;
        px.h[0] = (half2v){(_Float16)vx.x, (_Float16)vx.y};
        px.h[1] = (half2v){(_Float16)vx.z, (_Float16)vx.w};
        py.h[0] = (half2v){(_Float16)vy.x, (_Float16)vy.y};
        py.h[1] = (half2v){(_Float16)vy.z, (_Float16)vy.w};
        *(unsigned long long*)(xlds + r * XSTR + c4) = px.u;
        *(unsigned long long*)(ylds + r * YSTR + c4) = py.u;
    }
    __syncthreads();    // the ONLY barrier

    floatx4 acc[2][7];
#pragma unroll
    for (int rt = 0; rt < 2; ++rt)
#pragma unroll
        for (int ct = 0; ct < 7; ++ct)
            acc[rt][ct] = (floatx4){0.f, 0.f, 0.f, 0.f};

    const int rowb = rowhalf * 32 + li;
    const char* ybase[2];
    const char* xbase[2];
#pragma unroll
    for (int rt = 0; rt < 2; ++rt) {
        int row = rowb + rt * 16;
        ybase[rt] = (const char*)ylds + row * (YSTR * 2) + kg * 16;
        xbase[rt] = (const char*)xlds + row * (XSTR * 2);
    }
    const bool w1 = kg >= 1, w2 = kg >= 2, w3 = kg >= 3;

    // per-lane B-frag byte offset inside a global W chunk (16B-slot swizzle)
    const int bfoff = (obase + li) * 64 + ((kg ^ ((li >> 1) & 3)) * 16);

    const char* wb = (const char*)Wh;

    if (colgrp == 0)
        kloop<7>(wb, bfoff, ybase, xbase, w1, w2, w3, acc);
    else
        kloop<6>(wb, bfoff, ybase, xbase, w1, w2, w3, acc);

    // ---- epilogue: C/D layout col = lane&15, row = (lane>>4)*4 + reg  [m89]
#pragma unroll
    for (int rt = 0; rt < 2; ++rt) {
#pragma unroll
        for (int ct = 0; ct < 7; ++ct) {
            if (ct >= ntiles) continue;
            int gcol = obase + ct * 16 + li;
            if (gcol < OOv) {
#pragma unroll
                for (int r4 = 0; r4 < 4; ++r4) {
                    long grow = blockbase + rowhalf * 32 + rt * 16 + kg * 4 + r4;
                    Out[grow * OOv + gcol] = acc[rt][ct][r4];
                }
            }
        }
    }
}

extern "C" void kernel_launch(void* const* d_in, const int* in_sizes, int n_in,
                              void* d_out, int out_size, void* d_ws, size_t ws_size,
                              hipStream_t stream) {
    (void)in_sizes; (void)n_in; (void)out_size; (void)ws_size;
    const float* X = (const float*)d_in[0];
    const float* Y = (const float*)d_in[1];
    const float* W = (const float*)d_in[2];
    float* Out = (float*)d_out;
    unsigned short* Wh = (unsigned short*)d_ws;   // 665,600 B scratch

    wb_convert_kernel<<<1300, 256, 0, stream>>>(W, Wh);
    cin_mfma_kernel<<<1024, 256, 0, stream>>>(X, Y, Wh, Out);
}